// Round 23
// baseline (327.763 us; speedup 1.0000x reference)
//
#include <hip/hip_runtime.h>

// SpikeFFN: out = spike(LIF(x @ W1^T)) @ W2^T ; T=4 B=8 N=1024 C=512, fp32.
//
// HARD CONSTRAINT (r8): GEMM1 = single full-K ascending serial FMA chain per
// output in fp32 (np reference arithmetic); v_fma_f32 == CPU vfmadd.
// Tiling/load order free; per-output chain order is not.
//
// r13 (4w/SIMD) and r22 (8w/SIMD) both sit at VALUBusy ~66%: waves are
// tile-lockstepped and issue s_load/ds_read right before the lgkmcnt(0)
// drain that consumes them (distance ~0). r21's one-k-ahead pipeline was
// right but spilled at acc=32. r23 = r22's small footprint (acc 16) + the
// pipeline: aA/aB (f32x2, LDS) and bA/bB (f32x8, SGPR s_load) static
// ping-pong, issued >=16 FMAs before their drain. +2 VGPR, +16 SGPR.

typedef _Float16 half8  __attribute__((ext_vector_type(8)));
typedef _Float16 half4v __attribute__((ext_vector_type(4)));
typedef float    f32x2  __attribute__((ext_vector_type(2)));
typedef float    f32x4  __attribute__((ext_vector_type(4)));
typedef float    f32x8  __attribute__((ext_vector_type(8)));
typedef unsigned short ushort8 __attribute__((ext_vector_type(8)));

constexpr int TT   = 4;
constexpr int BB   = 8;
constexpr int NN   = 1024;
constexpr int CC   = 512;                 // Cin == Cout
constexpr int MROW = BB * NN;             // 8192 rows per timestep
constexpr int MTOT = TT * MROW;           // 32768 rows total
constexpr int BNC  = MROW * CC;           // per-timestep elems
constexpr int LDK  = 40;                  // fp16 LDS stride (gemm2)
constexpr int LTA2 = 130;                 // fp32 LDS row stride (128+2)

// --------------------------- W1 -> Wt[k][o] transpose ----------------------
__global__ __launch_bounds__(256)
void transpose_w(const float* __restrict__ W, float* __restrict__ Wt) {
    __shared__ float T[64][65];
    const int tid = threadIdx.x;
    const int bo  = blockIdx.x * 64;   // o tile
    const int bk  = blockIdx.y * 64;   // k tile
#pragma unroll
    for (int j = 0; j < 16; ++j) {
        int id = tid + 256 * j;
        int r = id >> 6, c = id & 63;              // r: o, c: k
        T[r][c] = W[(size_t)(bo + r) * CC + bk + c];
    }
    __syncthreads();
#pragma unroll
    for (int j = 0; j < 16; ++j) {
        int id = tid + 256 * j;
        int r = id >> 6, c = id & 63;              // r: k, c: o
        Wt[(size_t)(bk + r) * CC + bo + c] = T[c][r];
    }
}

// ---------- GEMM1: single full-K ascending serial FMA chain (fp32) ---------
// 128x64 block tile, 512 threads (8 waves x 8 cols), 2x8 outputs/thread.
// A: dbuf LDS, f32x2 lane reads, one-k-ahead into aA/aB.
// B: wave-uniform s_load f32x8, one-k-ahead into bA/bB (SGPR ping-pong).
__global__ __launch_bounds__(512, 8)
void gemm1_v23(const float* __restrict__ X, const float* __restrict__ Wt,
               float* __restrict__ H) {
#pragma clang fp contract(off)
    __shared__ float At[2][32][LTA2];   // 33.3 KB -> 4 blocks/CU

    const int tid  = threadIdx.x;
    const int lane = tid & 63;
    const int wid  = __builtin_amdgcn_readfirstlane(tid >> 6);  // 0..7 uniform
    const int RM   = blockIdx.x * 128;
    const int CN   = blockIdx.y * 64 + wid * 8;   // wave col base (uniform)
    const float* wcol = Wt + CN;                  // Wt[gk][CN..CN+7]

    const int srow = tid >> 2;           // staging row 0..127
    const int sk8  = (tid & 3) * 8;      // staging k base 0,8,16,24

    float acc[2][8] = {};                // ONE accumulator per output (16)
    f32x4 rx0, rx1;                      // A staging prefetch (VMEM)
    f32x2 aA, aB;                        // A ping-pong (LDS)
    f32x8 bA, bB;                        // B ping-pong (SGPR s_load)

#define FMA1(AR, BR)                                                        \
    {                                                                       \
        _Pragma("unroll")                                                   \
        for (int i = 0; i < 2; ++i) {                                       \
            _Pragma("unroll")                                               \
            for (int e = 0; e < 4; ++e) {                                   \
                acc[i][e]     = __builtin_fmaf(AR[i], BR[e],     acc[i][e]);\
                acc[i][4 + e] = __builtin_fmaf(AR[i], BR[4 + e],            \
                                               acc[i][4 + e]);              \
            }                                                               \
        }                                                                   \
    }

    // prologue: load + stage tile 0; preload k=0 operands
    rx0 = *(const f32x4*)&X[(size_t)(RM + srow) * CC + sk8];
    rx1 = *(const f32x4*)&X[(size_t)(RM + srow) * CC + sk8 + 4];
#pragma unroll
    for (int e = 0; e < 4; ++e) {
        At[0][sk8 + e][srow]     = rx0[e];
        At[0][sk8 + 4 + e][srow] = rx1[e];
    }
    __syncthreads();
    aA = *(const f32x2*)&At[0][0][lane * 2];
    bA = *(const f32x8*)&wcol[0];

    for (int kt = 0; kt < 16; ++kt) {
        const int cur = kt & 1;
        const int kb  = kt * 32;
        // issue A staging loads for tile kt+1 (VMEM; lands under FMAs)
        if (kt < 15) {
            int kk = (kt + 1) * 32;
            rx0 = *(const f32x4*)&X[(size_t)(RM + srow) * CC + kk + sk8];
            rx1 = *(const f32x4*)&X[(size_t)(RM + srow) * CC + kk + sk8 + 4];
        }
        // steady state: k = 0..29 (consume slot, refill one k ahead)
#pragma unroll 1
        for (int k = 0; k < 30; k += 2) {
            FMA1(aA, bA)                                          // k
            aB = *(const f32x2*)&At[cur][k + 1][lane * 2];
            bB = *(const f32x8*)&wcol[(size_t)(kb + k + 1) * CC];
            FMA1(aB, bB)                                          // k+1
            aA = *(const f32x2*)&At[cur][k + 2][lane * 2];
            bA = *(const f32x8*)&wcol[(size_t)(kb + k + 2) * CC];
        }
        // tile edge: k = 30, 31 (b prefetch crosses into next tile's row 0;
        // kt=15 loads pad row 512, never used)
        FMA1(aA, bA)                                              // k=30
        aB = *(const f32x2*)&At[cur][31][lane * 2];
        bB = *(const f32x8*)&wcol[(size_t)(kb + 31) * CC];
        FMA1(aB, bB)                                              // k=31
        bA = *(const f32x8*)&wcol[(size_t)(kb + 32) * CC];

        // stage tile kt+1 into the other buffer; a(k=0) read after barrier
        if (kt < 15) {
#pragma unroll
            for (int e = 0; e < 4; ++e) {
                At[cur ^ 1][sk8 + e][srow]     = rx0[e];
                At[cur ^ 1][sk8 + 4 + e][srow] = rx1[e];
            }
            __syncthreads();
            aA = *(const f32x2*)&At[cur ^ 1][0][lane * 2];
        }
    }
#undef FMA1

#pragma unroll
    for (int i = 0; i < 2; ++i) {
        size_t base = (size_t)(RM + lane * 2 + i) * CC + CN;
        f32x4 o0 = {acc[i][0], acc[i][1], acc[i][2], acc[i][3]};
        f32x4 o1 = {acc[i][4], acc[i][5], acc[i][6], acc[i][7]};
        *(f32x4*)&H[base]     = o0;
        *(f32x4*)&H[base + 4] = o1;
    }
}

// ----------------------------- LIF (fp32, np-op-exact) ---------------------
// Spike byte: 0x3C (= high byte of fp16 1.0) or 0x00.
__global__ __launch_bounds__(256)
void lif_np(const float* __restrict__ H, unsigned char* __restrict__ S8) {
#pragma clang fp contract(off)
    int g = blockIdx.x * 256 + threadIdx.x;   // 0 .. BNC/4-1
    float v[4] = {0.f, 0.f, 0.f, 0.f};
#pragma unroll
    for (int t = 0; t < TT; ++t) {
        f32x4 h = *(const f32x4*)&H[(size_t)t * BNC + (size_t)g * 4];
        unsigned int pack = 0;
#pragma unroll
        for (int e = 0; e < 4; ++e) {
            float d  = h[e] - v[e];          // rounded sub (np: x - (v-0))
            float d2 = d * 0.5f;             // exact (np: /2.0)
            v[e] = v[e] + d2;                // rounded add
            bool sp = v[e] >= 1.0f;
            if (sp) { pack |= 0x3Cu << (8 * e); v[e] = 0.0f; }
        }
        *(unsigned int*)&S8[(size_t)t * BNC + (size_t)g * 4] = pack;
    }
}

// ---------------------------------------------------------------- GEMM2 ----
// O[m][p] = sum_o S[m][o] * W2[p][o]. fp16 MFMA; spikes exact in fp16.
__global__ __launch_bounds__(256)
void gemm2_f16(const unsigned char* __restrict__ S8, const float* __restrict__ W,
               float* __restrict__ O) {
    __shared__ _Float16 As[128][LDK], Bs[128][LDK];

    const int tid  = threadIdx.x;
    const int RM   = blockIdx.x * 128;
    const int CN   = blockIdx.y * 128;
    const int lane = tid & 63;
    const int wv   = tid >> 6;
    const int wr   = (wv >> 1) * 64;
    const int wc   = (wv & 1) * 64;
    const int r15  = lane & 15;
    const int kg   = lane >> 4;

    f32x4 acc[4][4] = {};

    for (int k0 = 0; k0 < CC; k0 += 32) {
        __syncthreads();
#pragma unroll
        for (int j = 0; j < 2; ++j) {
            int id  = tid + 256 * j;
            int row = id >> 2;
            int c8  = (id & 3) * 8;
            unsigned long long v =
                *(const unsigned long long*)&S8[(size_t)(RM + row) * CC + k0 + c8];
            ushort8 u;
#pragma unroll
            for (int e = 0; e < 8; ++e)
                u[e] = (unsigned short)(((v >> (8 * e)) & 0xFFull) << 8);
            *(ushort8*)&As[row][c8] = u;
        }
#pragma unroll
        for (int j = 0; j < 4; ++j) {
            int id  = tid + 256 * j;
            int row = id >> 3;
            int c4  = (id & 7) * 4;
            f32x4 v = *(const f32x4*)&W[(size_t)(CN + row) * CC + k0 + c4];
            half4v hv;
#pragma unroll
            for (int e = 0; e < 4; ++e) hv[e] = (_Float16)v[e];
            *(half4v*)&Bs[row][c4] = hv;
        }
        __syncthreads();

        half8 a[4], b[4];
#pragma unroll
        for (int i = 0; i < 4; ++i) {
            a[i] = *(const half8*)&As[wr + i * 16 + r15][kg * 8];
            b[i] = *(const half8*)&Bs[wc + i * 16 + r15][kg * 8];
        }
#pragma unroll
        for (int i = 0; i < 4; ++i)
#pragma unroll
            for (int j = 0; j < 4; ++j)
                acc[i][j] = __builtin_amdgcn_mfma_f32_16x16x32_f16(a[i], b[j], acc[i][j], 0, 0, 0);
    }

#pragma unroll
    for (int i = 0; i < 4; ++i)
#pragma unroll
        for (int j = 0; j < 4; ++j)
#pragma unroll
            for (int r = 0; r < 4; ++r) {
                int gm = RM + wr + i * 16 + kg * 4 + r;
                int gn = CN + wc + j * 16 + r15;
                O[(size_t)gm * CC + gn] = acc[i][j][r];
            }
}

// -------------------------------------------------------------- launch -----
extern "C" void kernel_launch(void* const* d_in, const int* in_sizes, int n_in,
                              void* d_out, int out_size, void* d_ws, size_t ws_size,
                              hipStream_t stream) {
    const float* x  = (const float*)d_in[0];
    const float* W1 = (const float*)d_in[1];
    const float* W2 = (const float*)d_in[2];
    float* out = (float*)d_out;

    float*         h  = out;                                   // fp32 h in d_out
    unsigned char* s8 = (unsigned char*)d_ws;                  // spikes, 16 MB
    float*         wt = (float*)((char*)d_ws + (size_t)BNC);   // Wt, 512+1 rows

    dim3 gt(CC / 64, CC / 64);       // (8, 8)
    transpose_w<<<gt, 256, 0, stream>>>(W1, wt);

    dim3 g1(MTOT / 128, CC / 64);    // (256, 8) = 2048 blocks
    gemm1_v23<<<g1, 512, 0, stream>>>(x, wt, h);

    lif_np<<<BNC / 4 / 256, 256, 0, stream>>>(h, s8);

    dim3 g2(MTOT / 128, CC / 128);   // (256, 4)
    gemm2_f16<<<g2, 256, 0, stream>>>(s8, W2, out);
}